// Round 7
// baseline (134.443 us; speedup 1.0000x reference)
//
#include <hip/hip_runtime.h>
#include <hip/hip_bf16.h>

#define NHEAD 4
#define FIN   768
#define FOUT  64
#define BSZ   4
#define NSEQ  2048
#define BH    (BSZ*NHEAD)
#define LOG2E 1.44269504088896f

typedef __attribute__((ext_vector_type(8)))  short bf16x8;   // MFMA A/B frag
typedef __attribute__((ext_vector_type(16))) float f32x16;   // MFMA 32x32 C/D
typedef __attribute__((ext_vector_type(8)))  unsigned short u16x8;
typedef __attribute__((ext_vector_type(4)))  unsigned short u16x4;
typedef __attribute__((ext_vector_type(4)))  unsigned u32x4;

__device__ __forceinline__ unsigned short f2bf(float f){
  unsigned b = __float_as_uint(f);
  return (unsigned short)((b + 0x7fffu + ((b >> 16) & 1u)) >> 16);
}
__device__ __forceinline__ unsigned fenc(float f){
  unsigned b = __float_as_uint(f);
  return (b & 0x80000000u) ? ~b : (b | 0x80000000u);
}
__device__ __forceinline__ float fdec(unsigned u){
  unsigned b = (u & 0x80000000u) ? (u ^ 0x80000000u) : ~u;
  return __uint_as_float(b);
}
__device__ __forceinline__ float fexp2(float x){
#if __has_builtin(__builtin_amdgcn_exp2f)
  return __builtin_amdgcn_exp2f(x);
#else
  return exp2f(x);
#endif
}
__device__ __forceinline__ unsigned pkbf(float lo, float hi){
#if __has_builtin(__builtin_amdgcn_cvt_pk_bf16_f32)
  typedef __attribute__((ext_vector_type(2))) __bf16 bf2;
  union { bf2 v; unsigned u; } cv;
  cv.v = __builtin_amdgcn_cvt_pk_bf16_f32(lo, hi);
  return cv.u;
#else
  return (unsigned)f2bf(lo) | ((unsigned)f2bf(hi) << 16);
#endif
}

// ---------------------------------------------------------------------------
// Prep: w fp32 [4][768][64] -> bf16 frag image, LINEAR chunks (read from L2
// as global B-frags; no LDS staging so no swizzle needed):
// addr = ((head*12 + panel)*64 + o)*128 + c*16, chunk c = k-local c*8..c*8+7.
// ---------------------------------------------------------------------------
__global__ __launch_bounds__(256) void k_prep_w(
    const float* __restrict__ w, unsigned short* __restrict__ wp,
    unsigned* __restrict__ dmaxe)
{
  if (blockIdx.x == 0 && blockIdx.y == 0 && threadIdx.x < BH)
    dmaxe[threadIdx.x] = 0;
  const int head = blockIdx.x, kt = blockIdx.y;
  #pragma unroll
  for (int p = 0; p < 2; ++p){
    int u = threadIdx.x + p*256;
    int o = u >> 3, c = u & 7;
    u16x8 pk;
    #pragma unroll
    for (int j = 0; j < 8; ++j)
      pk[j] = f2bf(w[((size_t)head*FIN + kt*64 + c*8 + j)*FOUT + o]);
    *(u16x8*)((char*)wp + ((size_t)((head*12 + kt)*64 + o))*128 + c*16) = pk;
  }
}

// ---------------------------------------------------------------------------
// Kernel A v3: h' = h @ w_head, 32x32x16 MFMA. A staged in 2x16KB LDS dbuf
// (xor-swizzled, conflict-free); B-frags read DIRECTLY from global (L2-hot
// 768KB image) -> LDS halved to 32KB, B staging + its conflicts gone.
// ---------------------------------------------------------------------------
__global__ __launch_bounds__(512, 4) void k_hprime(
    const float* __restrict__ h, const unsigned short* __restrict__ wp,
    const float* __restrict__ a_src, const float* __restrict__ a_dst,
    unsigned short* __restrict__ hpz2, float* __restrict__ srcv,
    float* __restrict__ dstv, unsigned* __restrict__ dmaxe)
{
  __shared__ __align__(16) char smem[32768];
  // A0@0, A1@16384; epilogue overlays: scratch@0 (16K), Tt@16384 (8K),
  // psumS@24576, psumD@25088
  float* psumS = (float*)(smem + 24576);
  float* psumD = (float*)(smem + 25088);
  char*  Tt    = smem + 16384;

  const int tid  = threadIdx.x;
  const int i0a  = blockIdx.x * 64;
  const int jbase = i0a & (NSEQ-1);
  const int head = blockIdx.y;
  const int wave = tid >> 6, lane = tid & 63;
  const int wm = wave & 1, wn = (wave >> 1) & 1, kw = wave >> 2;
  const int l32 = lane & 31, h32 = lane >> 5;

  f32x16 acc = {0,0,0,0,0,0,0,0,0,0,0,0,0,0,0,0};

  const int sr = tid >> 3, sc = tid & 7;
  const float* hA = h + (size_t)(i0a + sr)*FIN + sc*8;
  const char* wrow = (const char*)wp
      + ((size_t)(head*12*64) + wn*32 + l32)*128 + h32*16;
  const int aslot = (sc ^ (sr & 7)) << 4;

  float4 ra0 = *(const float4*)(hA);
  float4 ra1 = *(const float4*)(hA + 4);
  float4 ra2 = *(const float4*)(hA + 64);
  float4 ra3 = *(const float4*)(hA + 68);

  for (int it = 0; it < 6; ++it){
    char* Ab = smem + (it & 1)*16384;
    u32x4 pk0, pk1;
    pk0[0] = pkbf(ra0.x, ra0.y); pk0[1] = pkbf(ra0.z, ra0.w);
    pk0[2] = pkbf(ra1.x, ra1.y); pk0[3] = pkbf(ra1.z, ra1.w);
    pk1[0] = pkbf(ra2.x, ra2.y); pk1[1] = pkbf(ra2.z, ra2.w);
    pk1[2] = pkbf(ra3.x, ra3.y); pk1[3] = pkbf(ra3.z, ra3.w);
    *(u32x4*)(Ab + sr*256 + aslot)       = pk0;
    *(u32x4*)(Ab + sr*256 + 128 + aslot) = pk1;
    __syncthreads();
    if (it < 5){
      const float* an = hA + (it+1)*128;
      ra0 = *(const float4*)(an);      ra1 = *(const float4*)(an + 4);
      ra2 = *(const float4*)(an + 64); ra3 = *(const float4*)(an + 68);
    }
    // B-frags straight from global (chunk c = s*2 + h32 of panel 2it+kw)
    const char* wpan = wrow + (size_t)(2*it + kw)*8192;
    bf16x8 b0 = *(const bf16x8*)(wpan);
    bf16x8 b1 = *(const bf16x8*)(wpan + 32);
    bf16x8 b2 = *(const bf16x8*)(wpan + 64);
    bf16x8 b3 = *(const bf16x8*)(wpan + 96);
    const char* abase = Ab + (wm*32 + l32)*256 + kw*128;
    bf16x8 a0 = *(const bf16x8*)(abase + (((0 + h32) ^ (l32 & 7)) << 4));
    bf16x8 a1 = *(const bf16x8*)(abase + (((2 + h32) ^ (l32 & 7)) << 4));
    bf16x8 a2 = *(const bf16x8*)(abase + (((4 + h32) ^ (l32 & 7)) << 4));
    bf16x8 a3 = *(const bf16x8*)(abase + (((6 + h32) ^ (l32 & 7)) << 4));
    acc = __builtin_amdgcn_mfma_f32_32x32x16_bf16(a0, b0, acc, 0, 0, 0);
    acc = __builtin_amdgcn_mfma_f32_32x32x16_bf16(a1, b1, acc, 0, 0, 0);
    acc = __builtin_amdgcn_mfma_f32_32x32x16_bf16(a2, b2, acc, 0, 0, 0);
    acc = __builtin_amdgcn_mfma_f32_32x32x16_bf16(a3, b3, acc, 0, 0, 0);
  }

  // kw-merge via scratch@0 (A0: its last readers finished before loop exit)
  if (kw == 1) *(f32x16*)(smem + (size_t)((wave & 3)*64 + lane)*64) = acc;
  __syncthreads();
  if (kw == 0){
    acc += *(const f32x16*)(smem + (size_t)((wave & 3)*64 + lane)*64);
    const float as = a_src[head*64 + wn*32 + l32];
    const float ad = a_dst[head*64 + wn*32 + l32];
    #pragma unroll
    for (int rb = 0; rb < 4; ++rb){
      const int jb = wm*32 + rb*8 + h32*4;
      u16x4 c4;
      #pragma unroll
      for (int q = 0; q < 4; ++q){
        const float v = acc[rb*4 + q];
        c4[q] = f2bf(v);
        const float t = tanhf(v);
        float ps = t*as, pd = t*ad;
        ps += __shfl_xor(ps, 1);  ps += __shfl_xor(ps, 2);  ps += __shfl_xor(ps, 4);
        ps += __shfl_xor(ps, 8);  ps += __shfl_xor(ps, 16);
        pd += __shfl_xor(pd, 1);  pd += __shfl_xor(pd, 2);  pd += __shfl_xor(pd, 4);
        pd += __shfl_xor(pd, 8);  pd += __shfl_xor(pd, 16);
        if (l32 == 0){
          psumS[(jb + q)*2 + wn] = ps;
          psumD[(jb + q)*2 + wn] = pd;
        }
      }
      const int orow = wn*32 + l32;
      const int slot = ((jb >> 3) & 7) ^ (orow & 7);
      *(u16x4*)(Tt + orow*128 + slot*16 + (jb & 7)*2) = c4;
    }
  }
  __syncthreads();

  const int bh = (i0a >> 11)*NHEAD + head;
  {
    const int o = tid & 63, c = tid >> 6;
    u16x8 val = *(const u16x8*)(Tt + o*128 + ((c ^ (o & 7)) << 4));
    *(u16x8*)((char*)hpz2 + ((size_t)(bh*256 + (jbase >> 3) + c)*64 + o)*16) = val;
  }
  if (tid < 64){
    float sv = (psumS[tid*2] + psumS[tid*2 + 1]) * LOG2E;   // log2 domain
    float dv = (psumD[tid*2] + psumD[tid*2 + 1]) * LOG2E;
    srcv[(size_t)bh*NSEQ + jbase + tid] = sv;
    dstv[(size_t)bh*NSEQ + jbase + tid] = dv;
    float dmx = dv;
    dmx = fmaxf(dmx, __shfl_xor(dmx, 1));  dmx = fmaxf(dmx, __shfl_xor(dmx, 2));
    dmx = fmaxf(dmx, __shfl_xor(dmx, 4));  dmx = fmaxf(dmx, __shfl_xor(dmx, 8));
    dmx = fmaxf(dmx, __shfl_xor(dmx, 16)); dmx = fmaxf(dmx, __shfl_xor(dmx, 32));
    if (tid == 0) atomicMax(&dmaxe[bh], fenc(dmx));
  }
}

// ---------------------------------------------------------------------------
// Kernel B v3: register-direct P, LINEAR H staging (conflict-free), l in VALU
// (16 adds/window) to cut 16 VGPR -> __launch_bounds__(512,6), 3 blocks/CU.
// ---------------------------------------------------------------------------
__global__ __launch_bounds__(512, 6) void k_attn(
    const unsigned short* __restrict__ hpz2, const float* __restrict__ srcv,
    const float* __restrict__ dstv, const unsigned* __restrict__ dmaxe,
    const float* __restrict__ bias, float* __restrict__ out)
{
  __shared__ __align__(16) char smem[33792];   // H0@0, H1@16384, Lbuf@32768
  float* Lbuf = (float*)(smem + 32768);        // [8][32]

  const int tid = threadIdx.x;
  const int i0  = blockIdx.x * 64;
  const int bh  = blockIdx.y;
  const int wave = tid >> 6, lane = tid & 63;
  const int wm = wave & 1, jw = wave >> 1;
  const int l32 = lane & 31, h32 = lane >> 5;

  const float s2  = srcv[(size_t)bh*NSEQ + i0 + wm*32 + l32];
  const float dm2 = fdec(dmaxe[bh]);
  float m2 = s2 + dm2; m2 = fmaxf(m2, 0.2f*m2);          // exact row max (log2 dom)
  const float u_ = s2 - m2;            // lrelu(s+d)-m = max(u_+d, fma(0.2,d,v_))
  const float v_ = 0.2f*s2 - m2;
  const float* dst = dstv + (size_t)bh*NSEQ;

  const u16x8* gp = (const u16x8*)((const char*)hpz2 + (size_t)bh*256*64*16);

  f32x16 accO0 = {0,0,0,0,0,0,0,0,0,0,0,0,0,0,0,0};
  f32x16 accO1 = {0,0,0,0,0,0,0,0,0,0,0,0,0,0,0,0};
  float lpart = 0.f;

  // prologue: stage window 0 (linear)
  *(u16x8*)(smem + tid*16)              = gp[tid];
  *(u16x8*)(smem + (tid + 512)*16)      = gp[tid + 512];
  __syncthreads();

  for (int w = 0; w < 16; ++w){
    char* cur = smem + (w & 1)*16384;
    char* nxt = smem + ((w + 1) & 1)*16384;
    u16x8 r0, r1;
    if (w < 15){
      r0 = gp[(w+1)*1024 + tid];
      r1 = gp[(w+1)*1024 + tid + 512];
    }
    #pragma unroll
    for (int stl = 0; stl < 2; ++stl){
      const int Jl = jw*4 + stl*2 + h32;
      const int j0 = (w*16 + Jl)*8;
      float4 d0 = *(const float4*)(dst + j0);
      float4 d1 = *(const float4*)(dst + j0 + 4);
      float e0,e1,e2,e3,e4,e5,e6,e7;
      e0 = fexp2(fmaxf(u_ + d0.x, fmaf(0.2f, d0.x, v_)));
      e1 = fexp2(fmaxf(u_ + d0.y, fmaf(0.2f, d0.y, v_)));
      e2 = fexp2(fmaxf(u_ + d0.z, fmaf(0.2f, d0.z, v_)));
      e3 = fexp2(fmaxf(u_ + d0.w, fmaf(0.2f, d0.w, v_)));
      e4 = fexp2(fmaxf(u_ + d1.x, fmaf(0.2f, d1.x, v_)));
      e5 = fexp2(fmaxf(u_ + d1.y, fmaf(0.2f, d1.y, v_)));
      e6 = fexp2(fmaxf(u_ + d1.z, fmaf(0.2f, d1.z, v_)));
      e7 = fexp2(fmaxf(u_ + d1.w, fmaf(0.2f, d1.w, v_)));
      lpart += ((e0+e1)+(e2+e3)) + ((e4+e5)+(e6+e7));
      u32x4 pk;
      pk[0] = pkbf(e0, e1); pk[1] = pkbf(e2, e3);
      pk[2] = pkbf(e4, e5); pk[3] = pkbf(e6, e7);
      const bf16x8 pA = __builtin_bit_cast(bf16x8, pk);
      const bf16x8 bv0 = *(const bf16x8*)(cur + (Jl*64 +      l32)*16);
      const bf16x8 bv1 = *(const bf16x8*)(cur + (Jl*64 + 32 + l32)*16);
      accO0 = __builtin_amdgcn_mfma_f32_32x32x16_bf16(pA, bv0, accO0, 0, 0, 0);
      accO1 = __builtin_amdgcn_mfma_f32_32x32x16_bf16(pA, bv1, accO1, 0, 0, 0);
    }
    if (w < 15){
      *(u16x8*)(nxt + tid*16)         = r0;
      *(u16x8*)(nxt + (tid + 512)*16) = r1;
    }
    __syncthreads();
  }

  // row l-sums: combine h32 halves, then per (wm,jw) into Lbuf
  lpart += __shfl_xor(lpart, 32);
  if (lane < 32) Lbuf[(wm*4 + jw)*32 + l32] = lpart;

  const float4 bia = *(const float4*)(bias + (tid & 15)*4);
  #pragma unroll
  for (int ph = 0; ph < 2; ++ph){
    __syncthreads();
    if (wm == ph){
      float* ob = (float*)smem;            // [jw][m 32][o 64] fp32 = 32 KB
      #pragma unroll
      for (int reg = 0; reg < 16; ++reg){
        const int m = (reg & 3) + 8*(reg >> 2) + 4*h32;
        ob[(jw*32 + m)*64 +      l32] = accO0[reg];
        ob[(jw*32 + m)*64 + 32 + l32] = accO1[reg];
      }
    }
    __syncthreads();
    {
      const int i = tid >> 4, o4 = (tid & 15)*4;
      const float* ob = (const float*)smem;
      float4 v0 = *(const float4*)(ob + (0*32 + i)*64 + o4);
      float4 v1 = *(const float4*)(ob + (1*32 + i)*64 + o4);
      float4 v2 = *(const float4*)(ob + (2*32 + i)*64 + o4);
      float4 v3 = *(const float4*)(ob + (3*32 + i)*64 + o4);
      const float l = Lbuf[(ph*4+0)*32 + i] + Lbuf[(ph*4+1)*32 + i]
                    + Lbuf[(ph*4+2)*32 + i] + Lbuf[(ph*4+3)*32 + i];
      const float r = 1.f / l;             // l >= 1 (exp2(0) term present)
      float4 res;
      res.x = (v0.x + v1.x + v2.x + v3.x)*r + bia.x;
      res.y = (v0.y + v1.y + v2.y + v3.y)*r + bia.y;
      res.z = (v0.z + v1.z + v2.z + v3.z)*r + bia.z;
      res.w = (v0.w + v1.w + v2.w + v3.w)*r + bia.w;
      *(float4*)(out + ((size_t)bh*NSEQ + i0 + ph*32 + i)*64 + o4) = res;
    }
  }
}

// ---------------------------------------------------------------------------
extern "C" void kernel_launch(void* const* d_in, const int* in_sizes, int n_in,
                              void* d_out, int out_size, void* d_ws, size_t ws_size,
                              hipStream_t stream)
{
  const float* h     = (const float*)d_in[0];
  const float* w     = (const float*)d_in[1];
  const float* a_src = (const float*)d_in[2];
  const float* a_dst = (const float*)d_in[3];
  const float* bias  = (const float*)d_in[4];
  float* out = (float*)d_out;

  char* ws = (char*)d_ws;
  unsigned short* hpz2 = (unsigned short*)ws;                           // 4 MB bf16 chunk-linear [16][256][64]
  float* srcv = (float*)(ws + (4u<<20));                                // 128 KB (log2-scaled)
  float* dstv = (float*)(ws + (4u<<20) + (128u<<10));                   // 128 KB (log2-scaled)
  unsigned short* wp = (unsigned short*)(ws + (4u<<20) + (256u<<10));   // 384 KB
  unsigned* dmaxe = (unsigned*)(ws + (4u<<20) + (640u<<10));            // 64 B

  k_prep_w<<<dim3(NHEAD, 12), 256, 0, stream>>>(w, wp, dmaxe);
  k_hprime<<<dim3(NSEQ*BSZ/64, NHEAD), 512, 0, stream>>>(h, wp, a_src, a_dst,
                                                         hpz2, srcv, dstv, dmaxe);
  k_attn<<<dim3(NSEQ/64, BH), 512, 0, stream>>>(hpz2, srcv, dstv, dmaxe, bias, out);
}